// Round 9
// baseline (538.989 us; speedup 1.0000x reference)
//
#include <hip/hip_runtime.h>
#include <hip/hip_bf16.h>
#include <cstdint>

#define B_ 16
#define C_ 256
#define CQ 32
#define H_ 96
#define W_ 96
#define HW 9216
#define NBAND 32
#define M_ 320

typedef unsigned short u16;
typedef short bf16x8 __attribute__((ext_vector_type(8)));
typedef float f32x4 __attribute__((ext_vector_type(4)));

__device__ inline u16 f2bf(float f) {
    uint32_t u = __float_as_uint(f);
    u += 0x7FFF + ((u >> 16) & 1);   // RNE
    return (u16)(u >> 16);
}
__device__ inline float bf2f(u16 s) {
    return __uint_as_float(((uint32_t)s) << 16);
}

__device__ inline void gload_lds16(const void* g, void* l) {
    __builtin_amdgcn_global_load_lds(
        (const __attribute__((address_space(1))) uint32_t*)g,
        (__attribute__((address_space(3))) uint32_t*)l, 16, 0, 0);
}

// ---------------- Kernel 0: pack W (f32, split q/k/v) -> Wb bf16 [320][256], biasb f32 [320]
__global__ __launch_bounds__(256) void wpack_kernel(
    const float* __restrict__ Wq, const float* __restrict__ bq,
    const float* __restrict__ Wk, const float* __restrict__ bk,
    const float* __restrict__ Wv, const float* __restrict__ bv,
    u16* __restrict__ Wb, float* __restrict__ biasb)
{
    int m = blockIdx.x;
    int t = threadIdx.x;
    const float* src = (m < 32) ? (Wq + m * 256)
                     : (m < 64) ? (Wk + (m - 32) * 256)
                                : (Wv + (m - 64) * 256);
    Wb[m * 256 + t] = f2bf(src[t]);
    if (t == 0) {
        biasb[m] = (m < 32) ? bq[m] : (m < 64) ? bk[m - 32] : bv[m - 64];
    }
}

// ---------------- Kernel 1: transpose + cast  x[b][c][s] f32 -> xT[b][s][c] bf16
// float4 loads; 16B (8-channel) uint4 stores.
__global__ __launch_bounds__(256) void xpose_kernel(const float* __restrict__ x,
                                                    u16* __restrict__ xT) {
    __shared__ float tile[64][65];
    int s0 = blockIdx.x * 64;
    int c0 = blockIdx.y * 64;
    int b  = blockIdx.z;
    int t = threadIdx.x;

    const float* xb = x + ((size_t)b * C_ + c0) * HW + s0;
    {
        int jj = (t & 15) * 4;      // col (s) within tile
        int i0 = t >> 4;            // 16 row groups of 4
        #pragma unroll
        for (int r = 0; r < 4; ++r) {
            int i = i0 * 4 + r;
            float4 f = *reinterpret_cast<const float4*>(&xb[(size_t)i * HW + jj]);
            tile[i][jj + 0] = f.x;
            tile[i][jj + 1] = f.y;
            tile[i][jj + 2] = f.z;
            tile[i][jj + 3] = f.w;
        }
    }
    __syncthreads();
    u16* xtb = xT + ((size_t)b * HW + s0) * C_ + c0;
    // 512 chunks (s 0..63 x 8 c-octets), 2 per thread; 16B stores.
    #pragma unroll
    for (int q = 0; q < 2; ++q) {
        int id = q * 256 + t;
        int s  = id >> 3;
        int c8 = (id & 7) * 8;
        uint4 pk;
        pk.x = (uint32_t)f2bf(tile[c8 + 0][s]) | ((uint32_t)f2bf(tile[c8 + 1][s]) << 16);
        pk.y = (uint32_t)f2bf(tile[c8 + 2][s]) | ((uint32_t)f2bf(tile[c8 + 3][s]) << 16);
        pk.z = (uint32_t)f2bf(tile[c8 + 4][s]) | ((uint32_t)f2bf(tile[c8 + 5][s]) << 16);
        pk.w = (uint32_t)f2bf(tile[c8 + 6][s]) | ((uint32_t)f2bf(tile[c8 + 7][s]) << 16);
        *reinterpret_cast<uint4*>(&xtb[(size_t)s * C_ + c8]) = pk;
    }
}

// ---------------- Kernel 2: qkv GEMM.  out[m][s] = sum_k Wb[m][k] * xT[s][k] + biasb[m]
// BM=320 (all of M), BN=128, BK=64. 512 threads = 8 waves as 2m x 4n.
// A: JIT register loads from L2-resident Wb (k-contiguous, 16B/lane).
// B: LDS double-buffer, global_load_lds w=16, XOR chunk swizzle; prefetch next
// k-step before the MFMA phase (2-phase pipeline).
__global__ __launch_bounds__(512, 4) void qkv_gemm_kernel(
    const u16* __restrict__ xT,
    const u16* __restrict__ Wb, const float* __restrict__ biasb,
    u16* __restrict__ qws, u16* __restrict__ kws,
    u16* __restrict__ vws)
{
    __shared__ u16 lB[2][128 * 64];   // 2 x 16 KB

    int s0 = blockIdx.x * 128;
    int b  = blockIdx.y;
    int t  = threadIdx.x;
    int w  = t >> 6, l = t & 63;
    int lr = l & 15, lg = l >> 4;
    int wm = w >> 2, wn = w & 3;   // wave tile: rows [wm*160, +160), cols [wn*32, +32)

    f32x4 acc[10][2] = {};

    int rsub = l >> 3;             // row within an 8-row issue group
    int cb   = l & 7;              // chunk within row
    const char* gB = (const char*)(xT + ((size_t)b * HW + s0) * C_);
    const u16* gA = Wb + (size_t)(wm * 160) * 256;

    // prologue: stage k0=0 into buf 0
    #pragma unroll
    for (int j = 0; j < 2; ++j) {
        int rbase = (w * 2 + j) * 8;
        int r = rbase + rsub;
        const char* src = gB + ((size_t)r * C_) * 2 + ((cb ^ (r & 7)) * 16);
        gload_lds16(src, (char*)lB[0] + rbase * 128);
    }
    __syncthreads();   // compiler emits vmcnt(0) drain before barrier

    int cur = 0;
    for (int k0 = 0; k0 < 256; k0 += 64) {
        if (k0 < 192) {   // prefetch next k-step into the other buffer
            #pragma unroll
            for (int j = 0; j < 2; ++j) {
                int rbase = (w * 2 + j) * 8;
                int r = rbase + rsub;
                const char* src = gB + ((size_t)r * C_ + (k0 + 64)) * 2 + ((cb ^ (r & 7)) * 16);
                gload_lds16(src, (char*)lB[cur ^ 1] + rbase * 128);
            }
        }
        #pragma unroll
        for (int ss = 0; ss < 2; ++ss) {
            int csw = (ss * 4 + lg) ^ (lr & 7);
            bf16x8 bfr[2];
            #pragma unroll
            for (int nf = 0; nf < 2; ++nf) {
                int r = wn * 32 + nf * 16 + lr;
                bfr[nf] = *reinterpret_cast<const bf16x8*>((char*)lB[cur] + r * 128 + csw * 16);
            }
            int koff = k0 + (ss * 4 + lg) * 8;
            #pragma unroll
            for (int mf = 0; mf < 10; ++mf) {
                bf16x8 af = *reinterpret_cast<const bf16x8*>(
                    gA + (size_t)(mf * 16 + lr) * 256 + koff);
                acc[mf][0] = __builtin_amdgcn_mfma_f32_16x16x32_bf16(af, bfr[0], acc[mf][0], 0, 0, 0);
                acc[mf][1] = __builtin_amdgcn_mfma_f32_16x16x32_bf16(af, bfr[1], acc[mf][1], 0, 0, 0);
            }
        }
        __syncthreads();   // drains prefetch writes (vmcnt 0) + separates buf reuse
        cur ^= 1;
    }

    // epilogue: D row = wm*160 + mf*16 + lg*4 + r, col = s0 + wn*32 + nf*16 + lr
    #pragma unroll
    for (int mf = 0; mf < 10; ++mf) {
        #pragma unroll
        for (int r = 0; r < 4; ++r) {
            int mg = wm * 160 + mf * 16 + lg * 4 + r;
            float bias = biasb[mg];
            #pragma unroll
            for (int nf = 0; nf < 2; ++nf) {
                int s = s0 + wn * 32 + nf * 16 + lr;
                float val = acc[mf][nf][r] + bias;
                if (mg < 32) {
                    qws[((size_t)b * CQ + mg) * HW + s] = f2bf(val);
                } else if (mg < 64) {
                    kws[((size_t)b * CQ + (mg - 32)) * HW + s] = f2bf(val);
                } else {
                    vws[((size_t)b * C_ + (mg - 64)) * HW + s] = f2bf(val);
                }
            }
        }
    }
}

// ---------------- Kernel 3a: per (b, band) attention weights -> wbuf
// wbuf[(b*32+n)*1728 + 0..863]   = ah[(w*3+kk)*3 + j]
// wbuf[(b*32+n)*1728 + 864..]    = av[(r*32+nw)*9 + kk*3 + jw]
__global__ __launch_bounds__(576) void attnw_kernel(
    const u16* __restrict__ qws, const u16* __restrict__ kws,
    float* __restrict__ wbuf)
{
    __shared__ __align__(16) u16 qkl[2 * CQ * 288];
    int n = blockIdx.x;
    int b = blockIdx.y;
    int t = threadIdx.x;

    u16* ql = qkl;
    u16* kl = qkl + CQ * 288;
    float* gw = wbuf + ((size_t)(b * NBAND + n)) * 1728;

    size_t qbase = (size_t)b * CQ * HW + (size_t)n * 288;   // element index
    // stage q,k as 16B chunks: 1152 chunks per array, 36 chunks per row of 288
    for (int ch = t; ch < 1152; ch += 576) {
        int cq = ch / 36, off = (ch - cq * 36) * 8;
        *reinterpret_cast<uint4*>(&ql[cq * 288 + off]) =
            *reinterpret_cast<const uint4*>(&qws[qbase + (size_t)cq * HW + off]);
        *reinterpret_cast<uint4*>(&kl[cq * 288 + off]) =
            *reinterpret_cast<const uint4*>(&kws[qbase + (size_t)cq * HW + off]);
    }
    __syncthreads();

    int item = t;
    if (item < 288) {
        int w = item % 96, kk = item / 96;
        float l0 = 0.f, l1 = 0.f, l2 = 0.f;
        for (int c = 0; c < CQ; ++c) {
            float qv = bf2f(ql[c * 288 + kk * 96 + w]);
            l0 += qv * bf2f(kl[c * 288 + w]);
            l1 += qv * bf2f(kl[c * 288 + 96 + w]);
            l2 += qv * bf2f(kl[c * 288 + 192 + w]);
        }
        float m = fmaxf(fmaxf(l0, l1), l2);
        float e0 = __expf(l0 - m), e1 = __expf(l1 - m), e2 = __expf(l2 - m);
        float inv = 1.0f / (e0 + e1 + e2);
        gw[(w * 3 + kk) * 3 + 0] = e0 * inv;
        gw[(w * 3 + kk) * 3 + 1] = e1 * inv;
        gw[(w * 3 + kk) * 3 + 2] = e2 * inv;
    } else {
        int it = item - 288;
        int r = it / 96, c2 = it - r * 96;
        int nw = c2 / 3, kk = c2 - nw * 3;
        int base = r * 96 + nw * 3;
        float l0 = 0.f, l1 = 0.f, l2 = 0.f;
        for (int c = 0; c < CQ; ++c) {
            float qv = bf2f(ql[c * 288 + base + kk]);
            l0 += qv * bf2f(kl[c * 288 + base + 0]);
            l1 += qv * bf2f(kl[c * 288 + base + 1]);
            l2 += qv * bf2f(kl[c * 288 + base + 2]);
        }
        float m = fmaxf(fmaxf(l0, l1), l2);
        float e0 = __expf(l0 - m), e1 = __expf(l1 - m), e2 = __expf(l2 - m);
        float inv = 1.0f / (e0 + e1 + e2);
        float* avp = gw + 864 + (r * 32 + nw) * 9 + kk * 3;
        avp[0] = e0 * inv;
        avp[1] = e1 * inv;
        avp[2] = e2 * inv;
    }
}

// ---------------- Kernel 3b: apply. One block per (b, band, 64-channel chunk).
// Thread owns (channel, nw 3-col group); 3x3 v(bf16)/x patch in registers; weights hoisted.
__global__ __launch_bounds__(256) void apply_kernel(
    const float* __restrict__ x,
    const u16* __restrict__ vws,
    const float* __restrict__ wbuf,
    const float* __restrict__ gamma,
    float* __restrict__ out)
{
    __shared__ float wsh[1728];     // ah [0,864), av [864,1728)
    int cc = blockIdx.x;            // 64-channel chunk
    int n  = blockIdx.y;
    int b  = blockIdx.z;
    int t  = threadIdx.x;
    float g = gamma[0];

    const float* gw = wbuf + ((size_t)(b * NBAND + n)) * 1728;
    for (int e = t; e < 432; e += 256)
        reinterpret_cast<float4*>(wsh)[e] = reinterpret_cast<const float4*>(gw)[e];
    __syncthreads();

    int lane = t & 63;
    int nw   = lane & 31;
    int half = lane >> 5;
    int wv   = t >> 6;

    // hoist weights: wa[jw][k][r] = ah[(nw*3+jw)*9 + k*3 + r]
    //                wb[r][k][jw] = av[(r*32+nw)*9 + k*3 + jw]
    float wa[3][3][3], wb[3][3][3];
    #pragma unroll
    for (int jw = 0; jw < 3; ++jw)
        #pragma unroll
        for (int k = 0; k < 3; ++k)
            #pragma unroll
            for (int r = 0; r < 3; ++r)
                wa[jw][k][r] = wsh[(nw * 3 + jw) * 9 + k * 3 + r];
    #pragma unroll
    for (int r = 0; r < 3; ++r)
        #pragma unroll
        for (int k = 0; k < 3; ++k)
            #pragma unroll
            for (int jw = 0; jw < 3; ++jw)
                wb[r][k][jw] = wsh[864 + (r * 32 + nw) * 9 + k * 3 + jw];

    #pragma unroll
    for (int i = 0; i < 8; ++i) {
        int c = cc * 64 + wv * 16 + i * 2 + half;
        size_t base  = ((size_t)b * C_ + c) * HW + (size_t)n * 288 + nw * 3;
        const u16* vp = vws + base;
        float v[3][3], xr[3][3];
        #pragma unroll
        for (int r = 0; r < 3; ++r) {
            #pragma unroll
            for (int jw = 0; jw < 3; ++jw) {
                v[r][jw]  = bf2f(vp[r * 96 + jw]);
                xr[r][jw] = x[base + r * 96 + jw];
            }
        }
        #pragma unroll
        for (int r = 0; r < 3; ++r) {
            #pragma unroll
            for (int jw = 0; jw < 3; ++jw) {
                float oh = v[0][jw] * wa[jw][0][r]
                         + v[1][jw] * wa[jw][1][r]
                         + v[2][jw] * wa[jw][2][r];
                float ov = v[r][0] * wb[r][0][jw]
                         + v[r][1] * wb[r][1][jw]
                         + v[r][2] * wb[r][2][jw];
                out[base + r * 96 + jw] = g * (oh + ov) + xr[r][jw];
            }
        }
    }
}

extern "C" void kernel_launch(void* const* d_in, const int* in_sizes, int n_in,
                              void* d_out, int out_size, void* d_ws, size_t ws_size,
                              hipStream_t stream) {
    const float* x     = (const float*)d_in[0];
    const float* Wq    = (const float*)d_in[1];
    const float* bq    = (const float*)d_in[2];
    const float* Wk    = (const float*)d_in[3];
    const float* bk    = (const float*)d_in[4];
    const float* Wv    = (const float*)d_in[5];
    const float* bv    = (const float*)d_in[6];
    const float* gamma = (const float*)d_in[7];
    float* out = (float*)d_out;

    u16* xT    = (u16*)d_ws;                                 // B*HW*C bf16  (75.5 MB)
    u16* qws   = xT + (size_t)B_ * HW * C_;                  // B*CQ*HW bf16 ( 9.4 MB)
    u16* kws   = qws + (size_t)B_ * CQ * HW;                 // B*CQ*HW bf16 ( 9.4 MB)
    u16* vws   = kws + (size_t)B_ * CQ * HW;                 // B*C*HW  bf16 (75.5 MB)
    u16* Wb    = vws + (size_t)B_ * C_ * HW;                 // 320*256 bf16 (160 KB)
    float* biasb = (float*)(Wb + (size_t)M_ * 256);          // 320 f32
    // weights buffer aliases the head of xT: xT is dead once the GEMM finishes.
    float* wbuf = (float*)d_ws;                              // 512*1728 f32 (3.54 MB)

    wpack_kernel<<<dim3(M_), 256, 0, stream>>>(Wq, bq, Wk, bk, Wv, bv, Wb, biasb);
    xpose_kernel<<<dim3(HW / 64, C_ / 64, B_), 256, 0, stream>>>(x, xT);
    qkv_gemm_kernel<<<dim3(HW / 128, B_), 512, 0, stream>>>(
        xT, Wb, biasb, qws, kws, vws);
    attnw_kernel<<<dim3(NBAND, B_), 576, 0, stream>>>(qws, kws, wbuf);
    apply_kernel<<<dim3(C_ / 64, NBAND, B_), 256, 0, stream>>>(x, vws, wbuf, gamma, out);
}

// Round 11
// 382.152 us; speedup vs baseline: 1.4104x; 1.4104x over previous
//
#include <hip/hip_runtime.h>
#include <hip/hip_bf16.h>
#include <cstdint>

#define B_ 16
#define C_ 256
#define CQ 32
#define H_ 96
#define W_ 96
#define HW 9216
#define NBAND 32
#define M_ 320

typedef unsigned short u16;
typedef short bf16x8 __attribute__((ext_vector_type(8)));
typedef float f32x4 __attribute__((ext_vector_type(4)));

__device__ inline u16 f2bf(float f) {
    uint32_t u = __float_as_uint(f);
    u += 0x7FFF + ((u >> 16) & 1);   // RNE
    return (u16)(u >> 16);
}
__device__ inline float bf2f(u16 s) {
    return __uint_as_float(((uint32_t)s) << 16);
}

__device__ inline void gload_lds16(const void* g, void* l) {
    __builtin_amdgcn_global_load_lds(
        (const __attribute__((address_space(1))) uint32_t*)g,
        (__attribute__((address_space(3))) uint32_t*)l, 16, 0, 0);
}

// ---------------- Kernel 0: pack W (f32, split q/k/v) -> Wb bf16 [320][256], biasb f32 [320]
__global__ __launch_bounds__(256) void wpack_kernel(
    const float* __restrict__ Wq, const float* __restrict__ bq,
    const float* __restrict__ Wk, const float* __restrict__ bk,
    const float* __restrict__ Wv, const float* __restrict__ bv,
    u16* __restrict__ Wb, float* __restrict__ biasb)
{
    int m = blockIdx.x;
    int t = threadIdx.x;
    const float* src = (m < 32) ? (Wq + m * 256)
                     : (m < 64) ? (Wk + (m - 32) * 256)
                                : (Wv + (m - 64) * 256);
    Wb[m * 256 + t] = f2bf(src[t]);
    if (t == 0) {
        biasb[m] = (m < 32) ? bq[m] : (m < 64) ? bk[m - 32] : bv[m - 64];
    }
}

// ---------------- Kernel 1: transpose + cast  x[b][c][s] f32 -> xT[b][s][c] bf16
// float4 loads; 16B (8-channel) uint4 stores.
__global__ __launch_bounds__(256) void xpose_kernel(const float* __restrict__ x,
                                                    u16* __restrict__ xT) {
    __shared__ float tile[64][65];
    int s0 = blockIdx.x * 64;
    int c0 = blockIdx.y * 64;
    int b  = blockIdx.z;
    int t = threadIdx.x;

    const float* xb = x + ((size_t)b * C_ + c0) * HW + s0;
    {
        int jj = (t & 15) * 4;      // col (s) within tile
        int i0 = t >> 4;            // 16 row groups of 4
        #pragma unroll
        for (int r = 0; r < 4; ++r) {
            int i = i0 * 4 + r;
            float4 f = *reinterpret_cast<const float4*>(&xb[(size_t)i * HW + jj]);
            tile[i][jj + 0] = f.x;
            tile[i][jj + 1] = f.y;
            tile[i][jj + 2] = f.z;
            tile[i][jj + 3] = f.w;
        }
    }
    __syncthreads();
    u16* xtb = xT + ((size_t)b * HW + s0) * C_ + c0;
    // 512 chunks (s 0..63 x 8 c-octets), 2 per thread; 16B stores.
    #pragma unroll
    for (int q = 0; q < 2; ++q) {
        int id = q * 256 + t;
        int s  = id >> 3;
        int c8 = (id & 7) * 8;
        uint4 pk;
        pk.x = (uint32_t)f2bf(tile[c8 + 0][s]) | ((uint32_t)f2bf(tile[c8 + 1][s]) << 16);
        pk.y = (uint32_t)f2bf(tile[c8 + 2][s]) | ((uint32_t)f2bf(tile[c8 + 3][s]) << 16);
        pk.z = (uint32_t)f2bf(tile[c8 + 4][s]) | ((uint32_t)f2bf(tile[c8 + 5][s]) << 16);
        pk.w = (uint32_t)f2bf(tile[c8 + 6][s]) | ((uint32_t)f2bf(tile[c8 + 7][s]) << 16);
        *reinterpret_cast<uint4*>(&xtb[(size_t)s * C_ + c8]) = pk;
    }
}

// ---------------- Kernel 2: qkv GEMM (round-8 known-good structure).
// out[m][s] = sum_k Wb[m][k] * xT[s][k] + biasb[m]
// BM=320 (all of M), BN=128, BK=64. 512 threads = 8 waves as 2m x 4n.
// LDS rows are 128B (64 bf16); 16B chunk c of row r stored at chunk c^(r&7).
__global__ __launch_bounds__(512, 4) void qkv_gemm_kernel(
    const u16* __restrict__ xT,
    const u16* __restrict__ Wb, const float* __restrict__ biasb,
    u16* __restrict__ qws, u16* __restrict__ kws,
    u16* __restrict__ vws)
{
    __shared__ u16 lA[M_ * 64];    // 40 KB
    __shared__ u16 lB[128 * 64];   // 16 KB

    int s0 = blockIdx.x * 128;
    int b  = blockIdx.y;
    int t  = threadIdx.x;
    int w  = t >> 6, l = t & 63;
    int lr = l & 15, lg = l >> 4;
    int wm = w >> 2, wn = w & 3;   // wave tile: rows [wm*160, +160), cols [wn*32, +32)

    f32x4 acc[10][2] = {};

    int rsub = l >> 3;             // row within an 8-row issue group
    int cb   = l & 7;              // chunk within row
    const char* gA = (const char*)Wb;
    const char* gB = (const char*)(xT + ((size_t)b * HW + s0) * C_);

    for (int k0 = 0; k0 < 256; k0 += 64) {
        // stage A: 40 issues (8 rows x 128B each), 5 per wave
        #pragma unroll
        for (int j = 0; j < 5; ++j) {
            int rbase = (w * 5 + j) * 8;
            int r = rbase + rsub;
            const char* src = gA + (size_t)r * 512 + k0 * 2 + ((cb ^ (r & 7)) * 16);
            gload_lds16(src, (char*)lA + rbase * 128);
        }
        // stage B: 16 issues, 2 per wave
        #pragma unroll
        for (int j = 0; j < 2; ++j) {
            int rbase = (w * 2 + j) * 8;
            int r = rbase + rsub;
            const char* src = gB + ((size_t)r * C_ + k0) * 2 + ((cb ^ (r & 7)) * 16);
            gload_lds16(src, (char*)lB + rbase * 128);
        }
        __syncthreads();

        #pragma unroll
        for (int ss = 0; ss < 2; ++ss) {
            int csw = (ss * 4 + lg) ^ (lr & 7);
            bf16x8 bfr[2];
            #pragma unroll
            for (int nf = 0; nf < 2; ++nf) {
                int r = wn * 32 + nf * 16 + lr;
                bfr[nf] = *reinterpret_cast<const bf16x8*>((char*)lB + r * 128 + csw * 16);
            }
            #pragma unroll
            for (int mf = 0; mf < 10; ++mf) {
                int r = wm * 160 + mf * 16 + lr;
                bf16x8 af = *reinterpret_cast<const bf16x8*>((char*)lA + r * 128 + csw * 16);
                acc[mf][0] = __builtin_amdgcn_mfma_f32_16x16x32_bf16(af, bfr[0], acc[mf][0], 0, 0, 0);
                acc[mf][1] = __builtin_amdgcn_mfma_f32_16x16x32_bf16(af, bfr[1], acc[mf][1], 0, 0, 0);
            }
        }
        __syncthreads();
    }

    // epilogue: D row = wm*160 + mf*16 + lg*4 + r, col = s0 + wn*32 + nf*16 + lr
    #pragma unroll
    for (int mf = 0; mf < 10; ++mf) {
        #pragma unroll
        for (int r = 0; r < 4; ++r) {
            int mg = wm * 160 + mf * 16 + lg * 4 + r;
            float bias = biasb[mg];
            #pragma unroll
            for (int nf = 0; nf < 2; ++nf) {
                int s = s0 + wn * 32 + nf * 16 + lr;
                float val = acc[mf][nf][r] + bias;
                if (mg < 32) {
                    qws[((size_t)b * CQ + mg) * HW + s] = f2bf(val);
                } else if (mg < 64) {
                    kws[((size_t)b * CQ + (mg - 32)) * HW + s] = f2bf(val);
                } else {
                    vws[((size_t)b * C_ + (mg - 64)) * HW + s] = f2bf(val);
                }
            }
        }
    }
}

// ---------------- Kernel 3a: per (b, band) attention weights -> wbuf
// wbuf[(b*32+n)*1728 + 0..863]   = ah[(w*3+kk)*3 + j]
// wbuf[(b*32+n)*1728 + 864..]    = av[(r*32+nw)*9 + kk*3 + jw]
__global__ __launch_bounds__(576) void attnw_kernel(
    const u16* __restrict__ qws, const u16* __restrict__ kws,
    float* __restrict__ wbuf)
{
    __shared__ __align__(16) u16 qkl[2 * CQ * 288];
    int n = blockIdx.x;
    int b = blockIdx.y;
    int t = threadIdx.x;

    u16* ql = qkl;
    u16* kl = qkl + CQ * 288;
    float* gw = wbuf + ((size_t)(b * NBAND + n)) * 1728;

    size_t qbase = (size_t)b * CQ * HW + (size_t)n * 288;   // element index
    // stage q,k as 16B chunks: 1152 chunks per array, 36 chunks per row of 288
    for (int ch = t; ch < 1152; ch += 576) {
        int cq = ch / 36, off = (ch - cq * 36) * 8;
        *reinterpret_cast<uint4*>(&ql[cq * 288 + off]) =
            *reinterpret_cast<const uint4*>(&qws[qbase + (size_t)cq * HW + off]);
        *reinterpret_cast<uint4*>(&kl[cq * 288 + off]) =
            *reinterpret_cast<const uint4*>(&kws[qbase + (size_t)cq * HW + off]);
    }
    __syncthreads();

    int item = t;
    if (item < 288) {
        int w = item % 96, kk = item / 96;
        float l0 = 0.f, l1 = 0.f, l2 = 0.f;
        for (int c = 0; c < CQ; ++c) {
            float qv = bf2f(ql[c * 288 + kk * 96 + w]);
            l0 += qv * bf2f(kl[c * 288 + w]);
            l1 += qv * bf2f(kl[c * 288 + 96 + w]);
            l2 += qv * bf2f(kl[c * 288 + 192 + w]);
        }
        float m = fmaxf(fmaxf(l0, l1), l2);
        float e0 = __expf(l0 - m), e1 = __expf(l1 - m), e2 = __expf(l2 - m);
        float inv = 1.0f / (e0 + e1 + e2);
        gw[(w * 3 + kk) * 3 + 0] = e0 * inv;
        gw[(w * 3 + kk) * 3 + 1] = e1 * inv;
        gw[(w * 3 + kk) * 3 + 2] = e2 * inv;
    } else {
        int it = item - 288;
        int r = it / 96, c2 = it - r * 96;
        int nw = c2 / 3, kk = c2 - nw * 3;
        int base = r * 96 + nw * 3;
        float l0 = 0.f, l1 = 0.f, l2 = 0.f;
        for (int c = 0; c < CQ; ++c) {
            float qv = bf2f(ql[c * 288 + base + kk]);
            l0 += qv * bf2f(kl[c * 288 + base + 0]);
            l1 += qv * bf2f(kl[c * 288 + base + 1]);
            l2 += qv * bf2f(kl[c * 288 + base + 2]);
        }
        float m = fmaxf(fmaxf(l0, l1), l2);
        float e0 = __expf(l0 - m), e1 = __expf(l1 - m), e2 = __expf(l2 - m);
        float inv = 1.0f / (e0 + e1 + e2);
        float* avp = gw + 864 + (r * 32 + nw) * 9 + kk * 3;
        avp[0] = e0 * inv;
        avp[1] = e1 * inv;
        avp[2] = e2 * inv;
    }
}

// ---------------- Kernel 3b: apply. One block per (b, band, 64-channel chunk).
// Thread owns (channel, nw 3-col group); 3x3 v(bf16)/x patch in registers; weights hoisted.
__global__ __launch_bounds__(256) void apply_kernel(
    const float* __restrict__ x,
    const u16* __restrict__ vws,
    const float* __restrict__ wbuf,
    const float* __restrict__ gamma,
    float* __restrict__ out)
{
    __shared__ float wsh[1728];     // ah [0,864), av [864,1728)
    int cc = blockIdx.x;            // 64-channel chunk
    int n  = blockIdx.y;
    int b  = blockIdx.z;
    int t  = threadIdx.x;
    float g = gamma[0];

    const float* gw = wbuf + ((size_t)(b * NBAND + n)) * 1728;
    for (int e = t; e < 432; e += 256)
        reinterpret_cast<float4*>(wsh)[e] = reinterpret_cast<const float4*>(gw)[e];
    __syncthreads();

    int lane = t & 63;
    int nw   = lane & 31;
    int half = lane >> 5;
    int wv   = t >> 6;

    // hoist weights: wa[jw][k][r] = ah[(nw*3+jw)*9 + k*3 + r]
    //                wb[r][k][jw] = av[(r*32+nw)*9 + k*3 + jw]
    float wa[3][3][3], wb[3][3][3];
    #pragma unroll
    for (int jw = 0; jw < 3; ++jw)
        #pragma unroll
        for (int k = 0; k < 3; ++k)
            #pragma unroll
            for (int r = 0; r < 3; ++r)
                wa[jw][k][r] = wsh[(nw * 3 + jw) * 9 + k * 3 + r];
    #pragma unroll
    for (int r = 0; r < 3; ++r)
        #pragma unroll
        for (int k = 0; k < 3; ++k)
            #pragma unroll
            for (int jw = 0; jw < 3; ++jw)
                wb[r][k][jw] = wsh[864 + (r * 32 + nw) * 9 + k * 3 + jw];

    #pragma unroll
    for (int i = 0; i < 8; ++i) {
        int c = cc * 64 + wv * 16 + i * 2 + half;
        size_t base  = ((size_t)b * C_ + c) * HW + (size_t)n * 288 + nw * 3;
        const u16* vp = vws + base;
        float v[3][3], xr[3][3];
        #pragma unroll
        for (int r = 0; r < 3; ++r) {
            #pragma unroll
            for (int jw = 0; jw < 3; ++jw) {
                v[r][jw]  = bf2f(vp[r * 96 + jw]);
                xr[r][jw] = x[base + r * 96 + jw];
            }
        }
        #pragma unroll
        for (int r = 0; r < 3; ++r) {
            #pragma unroll
            for (int jw = 0; jw < 3; ++jw) {
                float oh = v[0][jw] * wa[jw][0][r]
                         + v[1][jw] * wa[jw][1][r]
                         + v[2][jw] * wa[jw][2][r];
                float ov = v[r][0] * wb[r][0][jw]
                         + v[r][1] * wb[r][1][jw]
                         + v[r][2] * wb[r][2][jw];
                out[base + r * 96 + jw] = g * (oh + ov) + xr[r][jw];
            }
        }
    }
}

extern "C" void kernel_launch(void* const* d_in, const int* in_sizes, int n_in,
                              void* d_out, int out_size, void* d_ws, size_t ws_size,
                              hipStream_t stream) {
    const float* x     = (const float*)d_in[0];
    const float* Wq    = (const float*)d_in[1];
    const float* bq    = (const float*)d_in[2];
    const float* Wk    = (const float*)d_in[3];
    const float* bk    = (const float*)d_in[4];
    const float* Wv    = (const float*)d_in[5];
    const float* bv    = (const float*)d_in[6];
    const float* gamma = (const float*)d_in[7];
    float* out = (float*)d_out;

    u16* xT    = (u16*)d_ws;                                 // B*HW*C bf16  (75.5 MB)
    u16* qws   = xT + (size_t)B_ * HW * C_;                  // B*CQ*HW bf16 ( 9.4 MB)
    u16* kws   = qws + (size_t)B_ * CQ * HW;                 // B*CQ*HW bf16 ( 9.4 MB)
    u16* vws   = kws + (size_t)B_ * CQ * HW;                 // B*C*HW  bf16 (75.5 MB)
    u16* Wb    = vws + (size_t)B_ * C_ * HW;                 // 320*256 bf16 (160 KB)
    float* biasb = (float*)(Wb + (size_t)M_ * 256);          // 320 f32
    // weights buffer aliases the head of xT: xT is dead once the GEMM finishes.
    float* wbuf = (float*)d_ws;                              // 512*1728 f32 (3.54 MB)

    wpack_kernel<<<dim3(M_), 256, 0, stream>>>(Wq, bq, Wk, bk, Wv, bv, Wb, biasb);
    xpose_kernel<<<dim3(HW / 64, C_ / 64, B_), 256, 0, stream>>>(x, xT);
    qkv_gemm_kernel<<<dim3(HW / 128, B_), 512, 0, stream>>>(
        xT, Wb, biasb, qws, kws, vws);
    attnw_kernel<<<dim3(NBAND, B_), 576, 0, stream>>>(qws, kws, wbuf);
    apply_kernel<<<dim3(C_ / 64, NBAND, B_), 256, 0, stream>>>(x, vws, wbuf, gamma, out);
}